// Round 13
// baseline (141.080 us; speedup 1.0000x reference)
//
#include <hip/hip_runtime.h>
#include <hip/hip_bf16.h>
#include <limits.h>

typedef __attribute__((ext_vector_type(8))) short short8;
typedef __attribute__((ext_vector_type(4))) float f32x4;
typedef __attribute__((ext_vector_type(16))) float f32x16;

#define NN 8000
#define NCOL 4096      // 8*512 merged columns
#define KBINS 352      // NEST-1 == TOTAL_BINS
#define QPAD 640       // 583 padded
#define QH 320         // q rows per parity (u = q>>1)
#define BN 256         // cols per block
#define KC 8           // k chunks (grid 16x2x8 = 256 blocks = 1/CU)
#define NTILE 64       // shift-folded K padded: 64 tiles of 64 (n>=4000 zeroed)
#define KSTEP 8        // tiles per chunk: 64 = 8*8 exact
#define CUTQ 4
#define T_ 512
#define WFB 64         // packed band width for W_freq
#define WQB 20         // packed band width for W_quef

#define GLL16(g, l) __builtin_amdgcn_global_load_lds( \
    (const __attribute__((address_space(1))) unsigned int*)(g), \
    (__attribute__((address_space(3))) unsigned int*)(l), 16, 0, 0)

static __device__ __forceinline__ ushort bfc(float f){
  __hip_bfloat16 h = __float2bfloat16(f);
  return *reinterpret_cast<ushort*>(&h);
}
static __device__ __forceinline__ float b2f(ushort u){
  unsigned v = ((unsigned)u) << 16; float f; __builtin_memcpy(&f, &v, 4); return f;
}

// cosp[par][kt][u][64-swizzled] = bf16(cos(2pi*((2u+par)*n % 8000)/8000)),
// zero for q>=HQI or n>=4000. Slot s8 stored at s8^(u&7).
__global__ void gen_cos_k(ushort* __restrict__ cosp, int HQI){
  int n = blockIdx.x*256 + threadIdx.x;   // < 4096
  int u = blockIdx.y;                     // < 320
  int par = blockIdx.z;                   // < 2
  int q = 2*u + par;
  float v = 0.f;
  if (q < HQI && n < 4000){
    int m = (q*n) % NN;                            // exact integer angle reduction
    v = cosf((float)m * 7.8539816339744831e-4f);   // 2*pi/8000
  }
  int kt = n >> 6, s8 = (n >> 3) & 7, e = n & 7;
  cosp[((size_t)par*NTILE + kt)*(QH*64) + (size_t)u*64 + (((s8 ^ (u & 7)) << 3) | e)] = bfc(v);
}

// SHIFT-fold (no reflection, all reads forward-contiguous, no LDS, no barrier):
//   xe[n] = x[n] + x[n+4000], xo[n] = x[n] - x[n+4000]  (n < 4000; else 0)
// stored bf16, k-tiled & slot-swizzled: xs[par][kt][row][64], slot s8^(row&7).
__global__ __launch_bounds__(256) void prep_k(const float* __restrict__ dx,
                                              ushort* __restrict__ xs){
  int uid = blockIdx.x*256 + threadIdx.x;          // 4096 rows * 512 octets
  int row = uid >> 9;
  int n0 = (uid & 511) * 8;                        // 0..4088
  const float* rp = dx + (size_t)row*NN;
  short8 oe, oo;
  if (n0 < 4000){                                  // n0<=3992 -> idx<=7999, in-bounds
    f32x4 a0 = *(const f32x4*)(rp + n0);
    f32x4 a1 = *(const f32x4*)(rp + n0 + 4);
    f32x4 b0 = *(const f32x4*)(rp + 4000 + n0);
    f32x4 b1 = *(const f32x4*)(rp + 4004 + n0);
    #pragma unroll
    for (int e=0;e<4;e++){
      oe[e]   = (short)bfc(a0[e] + b0[e]);
      oo[e]   = (short)bfc(a0[e] - b0[e]);
      oe[4+e] = (short)bfc(a1[e] + b1[e]);
      oo[4+e] = (short)bfc(a1[e] - b1[e]);
    }
  } else {
    #pragma unroll
    for (int e=0;e<8;e++){ oe[e] = 0; oo[e] = 0; }
  }
  int kt = n0 >> 6, s8 = (n0 >> 3) & 7;
  size_t base = ((size_t)kt*NCOL + row)*64 + ((s8 ^ (row & 7)) << 3);
  *(short8*)(&xs[base]) = oe;                               // parity 0 (even q)
  *(short8*)(&xs[(size_t)NTILE*NCOL*64 + base]) = oo;       // parity 1 (odd q)
}

// bounds-scan + fixed-width transposed band-pack, both W matrices.
__global__ void bp_k(const float* __restrict__ Wf, const float* __restrict__ Wq,
                     int HFI, int HQI, int* __restrict__ fLo, int* __restrict__ qLo,
                     float* __restrict__ WfT, float* __restrict__ WqT){
  __shared__ int slo, shi;
  int r = blockIdx.x;
  bool isF = (blockIdx.y == 0);
  const float* W = isF ? Wf : Wq;
  int width = isF ? HFI : HQI;
  int bw    = isF ? WFB : WQB;
  float* WT = isF ? WfT : WqT;
  int* Lo   = isF ? fLo : qLo;
  if (threadIdx.x==0){ slo = INT_MAX; shi = -1; }
  __syncthreads();
  int mylo = INT_MAX, myhi = -1;
  for (int c = threadIdx.x; c < width; c += 256){
    if (W[(size_t)r*width + c] != 0.f){ if (c < mylo) mylo = c; if (c > myhi) myhi = c; }
  }
  atomicMin(&slo, mylo); atomicMax(&shi, myhi);
  __syncthreads();
  int l = (shi < 0) ? 0 : slo, h = (shi < 0) ? 0 : shi + 1;
  if (threadIdx.x==0) Lo[r] = l;
  for (int j = threadIdx.x; j < bw; j += 256){
    float v = 0.f;
    if (l + j < h) v = W[(size_t)r*width + l + j];
    WT[(size_t)j*KBINS + r] = v;
  }
}

// part[kc][col][par*320+u] (bf16) = sum_{k in chunk} xs[par][col][k]*cosp[par][u][k]
// Block 320u x 256col, BK=64, 8 waves (2 wm x 4 wn), wave tile 160u x 64col.
// dbuf 144KB LDS, 1 block/CU. Pure-GLL staging (wave-linear sources),
// counted vmcnt(9), 4 phase barriers/step.  [round-10/12 replay-proven structure]
__global__ __launch_bounds__(512, 2) void gemm_k(const ushort* __restrict__ xs,
                                                 const ushort* __restrict__ cosp,
                                                 ushort* __restrict__ part){
  __shared__ ushort As[2][QH*64];    // cos tiles, 40 KB each, slot-swizzled
  __shared__ ushort Bs[2][BN*64];    // folded dx tiles, 32 KB each, slot-swizzled
  int tid = threadIdx.x;
  int nb = blockIdx.x, par = blockIdx.y, kc = blockIdx.z;
  int lane = tid & 63, widx = tid >> 6;
  int wm = widx & 1, wn = widx >> 1;
  int l31 = lane & 31, lh = lane >> 5;
  int kt0 = kc*KSTEP, ktE = kt0 + KSTEP;

  const ushort* ag0 = cosp + (size_t)par*(NTILE*QH*64) + tid*8;
  const ushort* bg0 = xs + (size_t)par*(NTILE*NCOL*64) + (size_t)nb*(BN*64) + tid*8;

  #define STAGE(kt_, buf_) { \
    const ushort* ag_ = ag0 + (size_t)(kt_)*(QH*64); \
    _Pragma("unroll") \
    for (int i_=0;i_<5;i_++) GLL16(ag_ + i_*4096, &As[buf_][tid*8 + i_*4096]); \
    const ushort* bg_ = bg0 + (size_t)(kt_)*(NCOL*64); \
    _Pragma("unroll") \
    for (int i_=0;i_<4;i_++) GLL16(bg_ + i_*4096, &Bs[buf_][tid*8 + i_*4096]); }

  f32x16 acc[5][2];
  #pragma unroll
  for (int a=0;a<5;a++){ acc[a][0] = (f32x16)0.f; acc[a][1] = (f32x16)0.f; }

  STAGE(kt0, 0);                             // 9 loads/thread in flight

  int cur = 0;
  for (int kt = kt0; kt < ktE; ++kt){
    if (kt + 1 < ktE){
      STAGE(kt+1, cur^1);                    // 18 in flight
      asm volatile("s_waitcnt vmcnt(9)" ::: "memory");   // tile kt landed
    } else {
      asm volatile("s_waitcnt vmcnt(0)" ::: "memory");
    }
    __builtin_amdgcn_s_barrier();            // all waves see tile kt
    __builtin_amdgcn_sched_barrier(0);
    const ushort* Ac = &As[cur][0];
    const ushort* Bc = &Bs[cur][0];
    #pragma unroll
    for (int p=0;p<4;p++){                   // 4 k=16 phases within BK=64
      short8 dfr[2];
      #pragma unroll
      for (int c=0;c<2;c++){
        int row = wn*64 + c*32 + l31;
        dfr[c] = *(const short8*)(Bc + row*64 + ((((p<<1)|lh) ^ (row & 7)) << 3));
      }
      short8 cfr[5];
      #pragma unroll
      for (int a=0;a<5;a++){
        int row = wm*160 + a*32 + l31;
        cfr[a] = *(const short8*)(Ac + row*64 + ((((p<<1)|lh) ^ (row & 7)) << 3));
      }
      __builtin_amdgcn_s_setprio(1);
      #pragma unroll
      for (int a=0;a<5;a++){
        acc[a][0] = __builtin_amdgcn_mfma_f32_32x32x16_bf16(dfr[0], cfr[a], acc[a][0], 0,0,0);
        acc[a][1] = __builtin_amdgcn_mfma_f32_32x32x16_bf16(dfr[1], cfr[a], acc[a][1], 0,0,0);
      }
      __builtin_amdgcn_s_setprio(0);
      __builtin_amdgcn_sched_barrier(0);
      __builtin_amdgcn_s_barrier();          // phase lockstep (no vm drain)
      __builtin_amdgcn_sched_barrier(0);
    }
    cur ^= 1;
  }

  // D layout (32x32): n(u) = lane&31, m(col) = (r&3) + 8*(r>>2) + 4*(lane>>5)
  ushort* pb = part + (size_t)kc*NCOL*QPAD;
  #pragma unroll
  for (int a=0;a<5;a++){
    int slot = par*QH + wm*160 + a*32 + l31;        // q = 2u+par -> slot par*320+u
    #pragma unroll
    for (int c=0;c<2;c++){
      int colb = nb*BN + wn*64 + c*32 + 4*lh;
      #pragma unroll
      for (int r=0;r<16;r++){
        int col = colb + (r&3) + 8*(r>>2);
        pb[(size_t)col*QPAD + slot] = bfc(acc[a][c][r]);
      }
    }
  }
}

// per (b,t) column: partial-sum + nonlinear -> fixed-width banded matvecs -> harmonic gather
__global__ __launch_bounds__(384) void fuse_k(const float* __restrict__ dx,
        const ushort* __restrict__ part,
        const float* __restrict__ WfT, const float* __restrict__ WqT,
        const int* __restrict__ fLo, const int* __restrict__ qLo,
        float* __restrict__ out, int HFI, int HQI){
  __shared__ float xr[2368];
  __shared__ float yq[QPAD];
  __shared__ float tl0[KBINS];
  __shared__ float tlq[KBINS];
  int col = blockIdx.x;
  int b = col >> 9, t = col & 511;
  int tid = threadIdx.x;
  const float invs = 0.011180339887498949f;   // 1/sqrt(8000)

  for (int f = tid; f < 2368; f += 384) xr[f] = (f < HFI) ? dx[(size_t)col*NN + f] : 0.f;
  const ushort* pc = part + (size_t)col*QPAD;
  for (int q = tid; q < QPAD; q += 384){
    float y = 0.f;
    if (q < HQI){
      int slot = (q & 1)*QH + (q >> 1);       // parity-split slot mapping
      float s = 0.f;
      #pragma unroll
      for (int kc=0; kc<KC; kc++) s += b2f(pc[(size_t)kc*NCOL*QPAD + slot]);
      s *= invs;
      if (q >= CUTQ && s > 0.f) y = powf(s, 0.6f);
    }
    yq[q] = y;
  }
  __syncthreads();

  if (tid < KBINS){
    int k = tid;
    int lo = fLo[k];
    float aF = 0.f;
    #pragma unroll
    for (int j=0;j<WFB;j++) aF += WfT[j*KBINS + k] * xr[lo + j];
    int ql = qLo[k];
    float aQ = 0.f;
    #pragma unroll
    for (int j=0;j<WQB;j++) aQ += WqT[j*KBINS + k] * yq[ql + j];
    tl0[k] = aF; tlq[k] = aQ;
  }
  __syncthreads();

  const int hids[6] = {0,48,76,96,111,124};   // argmin|CF - (k+1)*27.5|
  for (int u = tid; u < 12*KBINS; u += 384){
    int j = u / KBINS;
    int k = u - j*KBINS;
    int h = hids[(j < 6) ? j : j - 6];
    float v;
    if (j < 6) v = (k + h < KBINS) ? tl0[k + h] : 0.f;   // har_s: shift left, pad end
    else       v = (k >= h)        ? tlq[k - h] : 0.f;   // har_c: shift right, pad front
    out[(((size_t)b*12 + j)*T_ + t)*KBINS + k] = v;
  }
}

extern "C" void kernel_launch(void* const* d_in, const int* in_sizes, int n_in,
                              void* d_out, int out_size, void* d_ws, size_t ws_size,
                              hipStream_t stream){
  const float* dx = (const float*)d_in[0];
  const float* Wf = (const float*)d_in[1];
  const float* Wq = (const float*)d_in[2];
  int HFI = in_sizes[1] / KBINS;   // runtime-derived (banker's-rounding safe)
  int HQI = in_sizes[2] / KBINS;
  float* out = (float*)d_out;
  char* ws = (char*)d_ws;

  ushort* cosp = (ushort*)ws;
  size_t off = (size_t)2*NTILE*QH*64*2;                        // 5.24 MB
  ushort* xs = (ushort*)(ws + off); off += (size_t)2*NTILE*NCOL*64*2;  // 67.1 MB
  ushort* part = (ushort*)(ws + off); off += (size_t)KC*NCOL*QPAD*2;   // 41.94 MB
  int* fLo = (int*)(ws+off); off += KBINS*4;
  int* qLo = (int*)(ws+off); off += KBINS*4;
  float* WfT = (float*)(ws+off); off += (size_t)WFB*KBINS*4;   // 90 KB
  float* WqT = (float*)(ws+off); off += (size_t)WQB*KBINS*4;   // 28 KB
  (void)n_in; (void)out_size; (void)ws_size;

  gen_cos_k<<<dim3(16, QH, 2), 256, 0, stream>>>(cosp, HQI);
  prep_k<<<NCOL*2, 256, 0, stream>>>(dx, xs);
  bp_k<<<dim3(KBINS, 2), 256, 0, stream>>>(Wf, Wq, HFI, HQI, fLo, qLo, WfT, WqT);
  gemm_k<<<dim3(NCOL/BN, 2, KC), 512, 0, stream>>>(xs, cosp, part);
  fuse_k<<<NCOL, 384, 0, stream>>>(dx, part, WfT, WqT, fLo, qLo, out, HFI, HQI);
}

// Round 14
// 127.858 us; speedup vs baseline: 1.1034x; 1.1034x over previous
//
#include <hip/hip_runtime.h>
#include <hip/hip_bf16.h>
#include <limits.h>

typedef __attribute__((ext_vector_type(8))) short short8;
typedef __attribute__((ext_vector_type(4))) float f32x4;
typedef __attribute__((ext_vector_type(16))) float f32x16;

#define NN 8000
#define NCOL 4096      // 8*512 merged columns
#define KBINS 352      // NEST-1 == TOTAL_BINS
#define QPAD 640       // 583 padded
#define QH 320         // q rows per block (2 q-halves)
#define BN 256         // cols per block
#define KC 8           // k chunks (grid 16x2x8 = 256 blocks = 1/CU)
#define NTILE 64       // folded K padded: 64 tiles of 64 (n>4000 zeroed)
#define KSTEP 8        // tiles per chunk: 64 = 8*8 exact
#define CUTQ 4
#define T_ 512
#define WFB 64         // packed band width for W_freq
#define WQB 20         // packed band width for W_quef
#define NFB 1024       // prep: fold blocks (4 rows each)
#define NCB 640        // prep: cos blocks (1 q each)

#define GLL16(g, l) __builtin_amdgcn_global_load_lds( \
    (const __attribute__((address_space(1))) unsigned int*)(g), \
    (__attribute__((address_space(3))) unsigned int*)(l), 16, 0, 0)

static __device__ __forceinline__ ushort bfc(float f){
  __hip_bfloat16 h = __float2bfloat16(f);
  return *reinterpret_cast<ushort*>(&h);
}
static __device__ __forceinline__ float b2f(ushort u){
  unsigned v = ((unsigned)u) << 16; float f; __builtin_memcpy(&f, &v, 4); return f;
}

// merged prep (one dispatch wave, all blocks co-resident):
//  blocks [0,NFB): reflection fold -> xf[kt][row][64-swizzled] bf16
//      xf[0]=x[0]; xf[n]=x[n]+x[8000-n] (1<=n<4000); xf[4000]=x[4000]; else 0
//      4 rows/block (wave w = row r0+w); lane processes 2 octets per unrolled
//      iter with ALL 10 global loads issued before any cvt/store (deep MLP).
//  blocks [NFB, NFB+NCB): cos table cosg[kt][q][64-swizzled]
//  rest: bounds-scan + transposed band-pack of Wf/Wq
__global__ __launch_bounds__(256) void prep_k(const float* __restrict__ dx,
        ushort* __restrict__ xf, ushort* __restrict__ cosg,
        const float* __restrict__ Wf, const float* __restrict__ Wq,
        int HFI, int HQI, int* __restrict__ fLo, int* __restrict__ qLo,
        float* __restrict__ WfT, float* __restrict__ WqT){
  int blk = blockIdx.x, t = threadIdx.x;
  if (blk < NFB){
    int w = t >> 6, l = t & 63;
    int row = blk*4 + w;
    const float* rp = dx + (size_t)row*NN;
    int swz = (row & 7) << 3;
    #pragma unroll
    for (int it=0; it<8; it+=2){
      int o0 = it*64 + l, o1 = o0 + 64;       // octets < 512
      int n0 = o0*8, n1 = o1*8;               // <= 4088: all addrs in-bounds
      // ---- load phase: 10 independent loads in flight ----
      f32x4 p00 = *(const f32x4*)(rp + n0);
      f32x4 p01 = *(const f32x4*)(rp + n0 + 4);
      f32x4 m0a = *(const f32x4*)(rp + 7996 - n0);
      f32x4 m0b = *(const f32x4*)(rp + 7992 - n0);
      float s0  = rp[n0 ? NN - n0 : 0];
      f32x4 p10 = *(const f32x4*)(rp + n1);
      f32x4 p11 = *(const f32x4*)(rp + n1 + 4);
      f32x4 m1a = *(const f32x4*)(rp + 7996 - n1);
      f32x4 m1b = *(const f32x4*)(rp + 7992 - n1);
      float s1  = rp[n1 ? NN - n1 : 0];
      // ---- fold + cvt + store octet 0 ----
      {
        float pr[8] = {p00[0],p00[1],p00[2],p00[3],p01[0],p01[1],p01[2],p01[3]};
        float mi[8] = {n0 ? s0 : 0.f, m0a[3],m0a[2],m0a[1],m0a[0],m0b[3],m0b[2],m0b[1]};
        short8 o;
        #pragma unroll
        for (int e=0;e<8;e++){
          int n = n0 + e;
          float v;
          if (n == 0)          v = pr[0];
          else if (n < 4000)   v = pr[e] + mi[e];
          else if (n == 4000)  v = pr[e];
          else                 v = 0.f;
          o[e] = (short)bfc(v);
        }
        int kt = n0 >> 6, s8 = (n0 >> 3) & 7;
        *(short8*)(&xf[((size_t)kt*NCOL + row)*64 + ((s8 << 3) ^ swz)]) = o;
      }
      // ---- fold + cvt + store octet 1 ----
      {
        float pr[8] = {p10[0],p10[1],p10[2],p10[3],p11[0],p11[1],p11[2],p11[3]};
        float mi[8] = {n1 ? s1 : 0.f, m1a[3],m1a[2],m1a[1],m1a[0],m1b[3],m1b[2],m1b[1]};
        short8 o;
        #pragma unroll
        for (int e=0;e<8;e++){
          int n = n1 + e;
          float v;
          if (n == 0)          v = pr[0];
          else if (n < 4000)   v = pr[e] + mi[e];
          else if (n == 4000)  v = pr[e];
          else                 v = 0.f;
          o[e] = (short)bfc(v);
        }
        int kt = n1 >> 6, s8 = (n1 >> 3) & 7;
        *(short8*)(&xf[((size_t)kt*NCOL + row)*64 + ((s8 << 3) ^ swz)]) = o;
      }
    }
  } else if (blk < NFB + NCB){
    int q = blk - NFB;
    int qz = (q < HQI) ? 1 : 0;
    #pragma unroll
    for (int h=0; h<2; ++h){                  // 2 octets per thread (16 n)
      int n0 = t*16 + h*8;                    // < 4096
      short8 o;
      #pragma unroll
      for (int e=0;e<8;e++){
        float v = 0.f;
        if (qz){
          int m = (q*(n0+e)) % NN;
          v = cosf((float)m * 7.8539816339744831e-4f);
        }
        o[e] = (short)bfc(v);
      }
      int kt = n0 >> 6, s8 = (n0 >> 3) & 7;
      *(short8*)(&cosg[(size_t)kt*(QPAD*64) + (size_t)q*64 + ((s8 ^ (q & 7)) << 3)]) = o;
    }
  } else {
    __shared__ int slo, shi;
    int u = blk - NFB - NCB;                  // 0..703
    int r = u >> 1;
    bool isF = (u & 1) == 0;
    const float* W = isF ? Wf : Wq;
    int width = isF ? HFI : HQI;
    int bw    = isF ? WFB : WQB;
    float* WT = isF ? WfT : WqT;
    int* Lo   = isF ? fLo : qLo;
    if (t==0){ slo = INT_MAX; shi = -1; }
    __syncthreads();
    int mylo = INT_MAX, myhi = -1;
    for (int c = t; c < width; c += 256){
      if (W[(size_t)r*width + c] != 0.f){ if (c < mylo) mylo = c; if (c > myhi) myhi = c; }
    }
    atomicMin(&slo, mylo); atomicMax(&shi, myhi);
    __syncthreads();
    int l = (shi < 0) ? 0 : slo, h = (shi < 0) ? 0 : shi + 1;
    if (t==0) Lo[r] = l;
    for (int j = t; j < bw; j += 256){
      float v = 0.f;
      if (l + j < h) v = W[(size_t)r*width + l + j];
      WT[(size_t)j*KBINS + r] = v;
    }
  }
}

// part[kc][col][q] (bf16) = sum_{k in chunk} xf[col][k]*cosg[q][k]
// Block 320q x 256col, BK=64, 8 waves (2 wm x 4 wn), wave tile 160q x 64col.
// dbuf 144KB LDS, 1 block/CU. Pure-GLL staging (wave-linear sources),
// counted vmcnt(9), 4 phase barriers/step.  [round-10/12/13 replay-proven]
__global__ __launch_bounds__(512, 2) void gemm_k(const ushort* __restrict__ xf,
                                                 const ushort* __restrict__ cosg,
                                                 ushort* __restrict__ part){
  __shared__ ushort As[2][QH*64];    // cos tiles, 40 KB each, slot-swizzled
  __shared__ ushort Bs[2][BN*64];    // folded dx tiles, 32 KB each, slot-swizzled
  int tid = threadIdx.x;
  int nb = blockIdx.x, qh = blockIdx.y, kc = blockIdx.z;
  int lane = tid & 63, widx = tid >> 6;
  int wm = widx & 1, wn = widx >> 1;
  int l31 = lane & 31, lh = lane >> 5;
  int kt0 = kc*KSTEP, ktE = kt0 + KSTEP;

  const ushort* ag0 = cosg + (size_t)qh*(QH*64) + tid*8;
  const ushort* bg0 = xf + (size_t)nb*(BN*64) + tid*8;

  #define STAGE(kt_, buf_) { \
    const ushort* ag_ = ag0 + (size_t)(kt_)*(QPAD*64); \
    _Pragma("unroll") \
    for (int i_=0;i_<5;i_++) GLL16(ag_ + i_*4096, &As[buf_][tid*8 + i_*4096]); \
    const ushort* bg_ = bg0 + (size_t)(kt_)*(NCOL*64); \
    _Pragma("unroll") \
    for (int i_=0;i_<4;i_++) GLL16(bg_ + i_*4096, &Bs[buf_][tid*8 + i_*4096]); }

  f32x16 acc[5][2];
  #pragma unroll
  for (int a=0;a<5;a++){ acc[a][0] = (f32x16)0.f; acc[a][1] = (f32x16)0.f; }

  STAGE(kt0, 0);                             // 9 loads/thread in flight

  int cur = 0;
  for (int kt = kt0; kt < ktE; ++kt){
    if (kt + 1 < ktE){
      STAGE(kt+1, cur^1);                    // 18 in flight
      asm volatile("s_waitcnt vmcnt(9)" ::: "memory");   // tile kt landed
    } else {
      asm volatile("s_waitcnt vmcnt(0)" ::: "memory");
    }
    __builtin_amdgcn_s_barrier();            // all waves see tile kt
    __builtin_amdgcn_sched_barrier(0);
    const ushort* Ac = &As[cur][0];
    const ushort* Bc = &Bs[cur][0];
    #pragma unroll
    for (int p=0;p<4;p++){                   // 4 k=16 phases within BK=64
      short8 dfr[2];
      #pragma unroll
      for (int c=0;c<2;c++){
        int row = wn*64 + c*32 + l31;
        dfr[c] = *(const short8*)(Bc + row*64 + ((((p<<1)|lh) ^ (row & 7)) << 3));
      }
      short8 cfr[5];
      #pragma unroll
      for (int a=0;a<5;a++){
        int row = wm*160 + a*32 + l31;
        cfr[a] = *(const short8*)(Ac + row*64 + ((((p<<1)|lh) ^ (row & 7)) << 3));
      }
      __builtin_amdgcn_s_setprio(1);
      #pragma unroll
      for (int a=0;a<5;a++){
        acc[a][0] = __builtin_amdgcn_mfma_f32_32x32x16_bf16(dfr[0], cfr[a], acc[a][0], 0,0,0);
        acc[a][1] = __builtin_amdgcn_mfma_f32_32x32x16_bf16(dfr[1], cfr[a], acc[a][1], 0,0,0);
      }
      __builtin_amdgcn_s_setprio(0);
      __builtin_amdgcn_sched_barrier(0);
      __builtin_amdgcn_s_barrier();          // phase lockstep (no vm drain)
      __builtin_amdgcn_sched_barrier(0);
    }
    cur ^= 1;
  }

  // D layout (32x32): n(q) = lane&31, m(col) = (r&3) + 8*(r>>2) + 4*(lane>>5)
  ushort* pb = part + (size_t)kc*NCOL*QPAD;
  #pragma unroll
  for (int a=0;a<5;a++){
    int q = qh*QH + wm*160 + a*32 + l31;
    #pragma unroll
    for (int c=0;c<2;c++){
      int colb = nb*BN + wn*64 + c*32 + 4*lh;
      #pragma unroll
      for (int r=0;r<16;r++){
        int col = colb + (r&3) + 8*(r>>2);
        pb[(size_t)col*QPAD + q] = bfc(acc[a][c][r]);
      }
    }
  }
}

// per (b,t) column: partial-sum + nonlinear -> fixed-width banded matvecs -> harmonic gather
__global__ __launch_bounds__(384) void fuse_k(const float* __restrict__ dx,
        const ushort* __restrict__ part,
        const float* __restrict__ WfT, const float* __restrict__ WqT,
        const int* __restrict__ fLo, const int* __restrict__ qLo,
        float* __restrict__ out, int HFI, int HQI){
  __shared__ float xr[2368];
  __shared__ float yq[QPAD];
  __shared__ float tl0[KBINS];
  __shared__ float tlq[KBINS];
  int col = blockIdx.x;
  int b = col >> 9, t = col & 511;
  int tid = threadIdx.x;
  const float invs = 0.011180339887498949f;   // 1/sqrt(8000)

  for (int f = tid; f < 2368; f += 384) xr[f] = (f < HFI) ? dx[(size_t)col*NN + f] : 0.f;
  const ushort* pc = part + (size_t)col*QPAD;
  for (int q = tid; q < QPAD; q += 384){
    float y = 0.f;
    if (q < HQI){
      float s = 0.f;
      #pragma unroll
      for (int kc=0; kc<KC; kc++) s += b2f(pc[(size_t)kc*NCOL*QPAD + q]);
      s *= invs;
      if (q >= CUTQ && s > 0.f) y = powf(s, 0.6f);
    }
    yq[q] = y;
  }
  __syncthreads();

  if (tid < KBINS){
    int k = tid;
    int lo = fLo[k];
    float aF = 0.f;
    #pragma unroll
    for (int j=0;j<WFB;j++) aF += WfT[j*KBINS + k] * xr[lo + j];
    int ql = qLo[k];
    float aQ = 0.f;
    #pragma unroll
    for (int j=0;j<WQB;j++) aQ += WqT[j*KBINS + k] * yq[ql + j];
    tl0[k] = aF; tlq[k] = aQ;
  }
  __syncthreads();

  const int hids[6] = {0,48,76,96,111,124};   // argmin|CF - (k+1)*27.5|
  for (int u = tid; u < 12*KBINS; u += 384){
    int j = u / KBINS;
    int k = u - j*KBINS;
    int h = hids[(j < 6) ? j : j - 6];
    float v;
    if (j < 6) v = (k + h < KBINS) ? tl0[k + h] : 0.f;   // har_s: shift left, pad end
    else       v = (k >= h)        ? tlq[k - h] : 0.f;   // har_c: shift right, pad front
    out[(((size_t)b*12 + j)*T_ + t)*KBINS + k] = v;
  }
}

extern "C" void kernel_launch(void* const* d_in, const int* in_sizes, int n_in,
                              void* d_out, int out_size, void* d_ws, size_t ws_size,
                              hipStream_t stream){
  const float* dx = (const float*)d_in[0];
  const float* Wf = (const float*)d_in[1];
  const float* Wq = (const float*)d_in[2];
  int HFI = in_sizes[1] / KBINS;   // runtime-derived (banker's-rounding safe)
  int HQI = in_sizes[2] / KBINS;
  float* out = (float*)d_out;
  char* ws = (char*)d_ws;

  ushort* cosg = (ushort*)ws;
  size_t off = (size_t)NTILE*QPAD*64*2;                        // 5.24 MB
  ushort* xf = (ushort*)(ws + off); off += (size_t)NTILE*NCOL*64*2;   // 33.55 MB
  ushort* part = (ushort*)(ws + off); off += (size_t)KC*NCOL*QPAD*2;  // 41.94 MB
  int* fLo = (int*)(ws+off); off += KBINS*4;
  int* qLo = (int*)(ws+off); off += KBINS*4;
  float* WfT = (float*)(ws+off); off += (size_t)WFB*KBINS*4;   // 90 KB
  float* WqT = (float*)(ws+off); off += (size_t)WQB*KBINS*4;   // 28 KB
  (void)n_in; (void)out_size; (void)ws_size;

  prep_k<<<NFB + NCB + 2*KBINS, 256, 0, stream>>>(dx, xf, cosg, Wf, Wq,
                                                  HFI, HQI, fLo, qLo, WfT, WqT);
  gemm_k<<<dim3(NCOL/BN, QPAD/QH, KC), 512, 0, stream>>>(xf, cosg, part);
  fuse_k<<<NCOL, 384, 0, stream>>>(dx, part, WfT, WqT, fLo, qLo, out, HFI, HQI);
}